// Round 10
// baseline (95.446 us; speedup 1.0000x reference)
//
#include <hip/hip_runtime.h>
#include <cstdint>

typedef float f32x4 __attribute__((ext_vector_type(4)));

constexpr int Bv = 32;      // batch rows (M)
constexpr int Hv = 4096;    // hidden (K1, N2)
constexpr int Iv = 2048;    // intermediate
constexpr int N1 = 4096;    // 2*I

// ---------------------------------------------------------------------------
// fp4 e2m1 word (8 nibbles, LSB-first along K) -> 8 fp8 e4m3 bytes (k-order)
// Magnitude LUT (idx 0-7): 0x00,0x30,0x38,0x3C,0x40,0x44,0x48,0x4C; sign->bit7.
// ---------------------------------------------------------------------------
__device__ __forceinline__ long dec8(uint32_t w) {
  uint32_t lo = w & 0x07070707u;          // mag idx n0,n2,n4,n6
  uint32_t hi = (w >> 4) & 0x07070707u;   // mag idx n1,n3,n5,n7
  uint32_t me = __builtin_amdgcn_perm(0x4C484440u, 0x3C383000u, lo);
  uint32_t mo = __builtin_amdgcn_perm(0x4C484440u, 0x3C383000u, hi);
  uint32_t e  = me | ((w & 0x08080808u) << 4);   // even nibbles + sign
  uint32_t o  = mo | (w & 0x80808080u);          // odd nibbles + sign
  uint32_t d0 = __builtin_amdgcn_perm(o, e, 0x05010400u);  // n0,n1,n2,n3
  uint32_t d1 = __builtin_amdgcn_perm(o, e, 0x07030602u);  // n4,n5,n6,n7
  return (long)(((uint64_t)d1 << 32) | d0);
}

// ---------------------------------------------------------------------------
// 8 consecutive f32 -> fp8 hi plane (8 bytes) + fp8 residual plane (8 bytes).
// ---------------------------------------------------------------------------
__device__ __forceinline__ void quant8(const float* p, long& hi, long& lo) {
  f32x4 a = *(const f32x4*)p;
  f32x4 b = *(const f32x4*)(p + 4);
  uint32_t h0 = 0, h1 = 0;
  h0 = __builtin_amdgcn_cvt_pk_fp8_f32(a[0], a[1], h0, false);
  h0 = __builtin_amdgcn_cvt_pk_fp8_f32(a[2], a[3], h0, true);
  h1 = __builtin_amdgcn_cvt_pk_fp8_f32(b[0], b[1], h1, false);
  h1 = __builtin_amdgcn_cvt_pk_fp8_f32(b[2], b[3], h1, true);
  float r0 = a[0] - __builtin_amdgcn_cvt_f32_fp8(h0, 0);
  float r1 = a[1] - __builtin_amdgcn_cvt_f32_fp8(h0, 1);
  float r2 = a[2] - __builtin_amdgcn_cvt_f32_fp8(h0, 2);
  float r3 = a[3] - __builtin_amdgcn_cvt_f32_fp8(h0, 3);
  float r4 = b[0] - __builtin_amdgcn_cvt_f32_fp8(h1, 0);
  float r5 = b[1] - __builtin_amdgcn_cvt_f32_fp8(h1, 1);
  float r6 = b[2] - __builtin_amdgcn_cvt_f32_fp8(h1, 2);
  float r7 = b[3] - __builtin_amdgcn_cvt_f32_fp8(h1, 3);
  uint32_t l0 = 0, l1 = 0;
  l0 = __builtin_amdgcn_cvt_pk_fp8_f32(r0, r1, l0, false);
  l0 = __builtin_amdgcn_cvt_pk_fp8_f32(r2, r3, l0, true);
  l1 = __builtin_amdgcn_cvt_pk_fp8_f32(r4, r5, l1, false);
  l1 = __builtin_amdgcn_cvt_pk_fp8_f32(r6, r7, l1, true);
  hi = (long)(((uint64_t)h1 << 32) | h0);
  lo = (long)(((uint64_t)l1 << 32) | l0);
}

// ---------------------------------------------------------------------------
// K1 (gate_up GEMM + SwiGLU fused, prep in-register):
// 256 wgs x 1024 thr (1 wg/CU, 4 waves/SIMD). wg = 8-act-col pair tile x
// full K(4096). B-fragment lanes 0-7 carry gate cols c0..c0+7, lanes 8-15
// carry up cols Iv+c0..Iv+c0+7 (one MFMA computes both). 16 waves = 256-k
// chunk each (2 scale groups, exact f32 scale FMA). 16-way LDS reduce puts
// g at col c, u at col c+8; epilogue does SwiGLU + two-term fp8 quant and
// writes act planes directly. Weights fetched exactly once device-wide.
// Layouts: A[m=lane&15][k=q*8+j]; B[k=q*8+j][n=lane&15]; C col=r,row=q*4+reg.
// ---------------------------------------------------------------------------
__global__ __launch_bounds__(1024, 4) void k_gu(
    const float* __restrict__ x, const uint32_t* __restrict__ wp,
    const float* __restrict__ sc, uint8_t* __restrict__ a8h,
    uint8_t* __restrict__ a8l) {
  __shared__ float lds[16 * 512];          // 32 KiB
  const int c0 = blockIdx.x * 8;           // act-col tile (0..2040)
  const int wid = threadIdx.x >> 6, lane = threadIdx.x & 63;
  const int q = lane >> 4, r = lane & 15;
  const int ncol = (r < 8) ? (c0 + r) : (Iv + c0 + (r - 8));

  const int koff = wid * 256 + q * 8;      // elem offset in K
  const float* px0 = x + r * Hv + koff;
  const float* px1 = x + (r + 16) * Hv + koff;
  const uint32_t* pb = wp + (size_t)(wid * 32 + q) * N1 + ncol;

  f32x4 acc0 = {0,0,0,0}, acc1 = {0,0,0,0};
  #pragma unroll
  for (int g = 0; g < 2; ++g) {            // 2 scale groups per wave
    f32x4 t0 = {0,0,0,0}, t1 = {0,0,0,0};
    #pragma unroll
    for (int st = 0; st < 4; ++st) {       // 4 x K=32 steps = one group
      const int ke = g * 128 + st * 32;
      long A0h, A0l, A1h, A1l;
      quant8(px0 + ke, A0h, A0l);
      quant8(px1 + ke, A1h, A1l);
      long B = dec8(pb[(size_t)(g * 16 + st * 4) * N1]);
      t0 = __builtin_amdgcn_mfma_f32_16x16x32_fp8_fp8(A0h, B, t0, 0, 0, 0);
      t0 = __builtin_amdgcn_mfma_f32_16x16x32_fp8_fp8(A0l, B, t0, 0, 0, 0);
      t1 = __builtin_amdgcn_mfma_f32_16x16x32_fp8_fp8(A1h, B, t1, 0, 0, 0);
      t1 = __builtin_amdgcn_mfma_f32_16x16x32_fp8_fp8(A1l, B, t1, 0, 0, 0);
    }
    const float s = sc[(wid * 2 + g) * N1 + ncol];
    #pragma unroll
    for (int j = 0; j < 4; ++j) {
      acc0[j] = fmaf(s, t0[j], acc0[j]);
      acc1[j] = fmaf(s, t1[j], acc1[j]);
    }
  }
  float* my = lds + wid * 512;
  #pragma unroll
  for (int j = 0; j < 4; ++j) {
    const int rw = q * 4 + j;
    my[rw * 16 + r]        = acc0[j];
    my[(16 + rw) * 16 + r] = acc1[j];
  }
  __syncthreads();
  const int i = threadIdx.x;
  if (i < 512) {                           // reduce 16 waves; red -> lds[i]
    float sum = 0.f;
    #pragma unroll
    for (int w = 0; w < 16; ++w) sum += lds[w * 512 + i];
    lds[i] = sum;    // safe: lds[i] read only by thread i (w=0), sequenced
  }
  __syncthreads();
  if (i < 256) {                           // 32 rows x 8 act cols
    const int row = i >> 3, c = i & 7;
    const float gv = lds[row * 16 + c];
    const float uv = lds[row * 16 + 8 + c];
    float av = gv / (1.0f + __expf(-gv)) * uv;
    av = fminf(fmaxf(av, -440.0f), 440.0f);       // e4m3 NaN armor
    uint32_t hb = __builtin_amdgcn_cvt_pk_fp8_f32(av, av, 0, false);
    float rv = av - __builtin_amdgcn_cvt_f32_fp8(hb, 0);
    uint32_t lb = __builtin_amdgcn_cvt_pk_fp8_f32(rv, rv, 0, false);
    const int off = row * Iv + c0 + c;
    a8h[off] = (uint8_t)(hb & 0xFF);
    a8l[off] = (uint8_t)(lb & 0xFF);
  }
}

// ---------------------------------------------------------------------------
// K2: out f32 [32][4096] = act[32,2048] @ dequant(W_down).
// 256 wgs x 1024 thr: wg = 16-col tile x full K(2048). 16 waves = one scale
// group each; both row-tiles per wave; 16-way LDS reduce; direct f32 out.
// ---------------------------------------------------------------------------
__global__ __launch_bounds__(1024, 4) void k_down(
    const uint8_t* __restrict__ ah8, const uint8_t* __restrict__ al8,
    const uint32_t* __restrict__ wp, const float* __restrict__ sc,
    float* __restrict__ out) {
  __shared__ float lds[16 * 512];
  const int n0 = blockIdx.x * 16;
  const int wid = threadIdx.x >> 6, lane = threadIdx.x & 63;
  const int q = lane >> 4, r = lane & 15;
  const int n = n0 + r;

  const int koff = wid * 128 + q * 8;
  const uint8_t* pa0h = ah8 + r * Iv + koff;
  const uint8_t* pa0l = al8 + r * Iv + koff;
  const uint8_t* pa1h = ah8 + (r + 16) * Iv + koff;
  const uint8_t* pa1l = al8 + (r + 16) * Iv + koff;
  const uint32_t* pb = wp + (size_t)(wid * 16 + q) * Hv + n;

  f32x4 t0 = {0,0,0,0}, t1 = {0,0,0,0};
  #pragma unroll
  for (int st = 0; st < 4; ++st) {
    long A0h = *(const long*)(pa0h + st * 32);
    long A0l = *(const long*)(pa0l + st * 32);
    long A1h = *(const long*)(pa1h + st * 32);
    long A1l = *(const long*)(pa1l + st * 32);
    long Bf = dec8(pb[(size_t)st * 4 * Hv]);
    t0 = __builtin_amdgcn_mfma_f32_16x16x32_fp8_fp8(A0h, Bf, t0, 0, 0, 0);
    t0 = __builtin_amdgcn_mfma_f32_16x16x32_fp8_fp8(A0l, Bf, t0, 0, 0, 0);
    t1 = __builtin_amdgcn_mfma_f32_16x16x32_fp8_fp8(A1h, Bf, t1, 0, 0, 0);
    t1 = __builtin_amdgcn_mfma_f32_16x16x32_fp8_fp8(A1l, Bf, t1, 0, 0, 0);
  }
  const float sv = sc[wid * Hv + n];
  float* my = lds + wid * 512;
  #pragma unroll
  for (int j = 0; j < 4; ++j) {
    const int rw = q * 4 + j;
    my[rw * 16 + r]        = sv * t0[j];
    my[(16 + rw) * 16 + r] = sv * t1[j];
  }
  __syncthreads();
  const int i = threadIdx.x;
  if (i < 512) {                            // 512 outputs (32x16)
    float sum = 0.f;
    #pragma unroll
    for (int w = 0; w < 16; ++w) sum += lds[w * 512 + i];
    out[(i >> 4) * N1 + n0 + (i & 15)] = sum;
  }
}

// ---------------------------------------------------------------------------
extern "C" void kernel_launch(void* const* d_in, const int* in_sizes, int n_in,
                              void* d_out, int out_size, void* d_ws, size_t ws_size,
                              hipStream_t stream) {
  // Harness promotes float16 tensors to float32. x, scales, out are f32.
  const float*    x   = (const float*)d_in[0];      // f32 [32,4096]
  const uint32_t* gup = (const uint32_t*)d_in[1];   // [512,4096] packed fp4
  const float*    gus = (const float*)d_in[2];      // f32 [32,4096]
  const uint32_t* dnp = (const uint32_t*)d_in[3];   // [256,4096] packed fp4
  const float*    dns = (const float*)d_in[4];      // f32 [16,4096]

  uint8_t* a8h = (uint8_t*)d_ws;                    // 64 KiB
  uint8_t* a8l = a8h + Bv*Iv;                       // 64 KiB

  k_gu  <<<256, 1024, 0, stream>>>(x, gup, gus, a8h, a8l);
  k_down<<<256, 1024, 0, stream>>>(a8h, a8l, dnp, dns, (float*)d_out);
}

// Round 11
// 90.503 us; speedup vs baseline: 1.0546x; 1.0546x over previous
//
#include <hip/hip_runtime.h>
#include <cstdint>

typedef float f32x4 __attribute__((ext_vector_type(4)));

constexpr int Bv = 32;      // batch rows (M)
constexpr int Hv = 4096;    // hidden (K1, N2)
constexpr int Iv = 2048;    // intermediate
constexpr int N1 = 4096;    // 2*I

// ---------------------------------------------------------------------------
// fp4 e2m1 word (8 nibbles, LSB-first along K) -> 8 fp8 e4m3 bytes (k-order)
// Magnitude LUT (idx 0-7): 0x00,0x30,0x38,0x3C,0x40,0x44,0x48,0x4C; sign->bit7.
// ---------------------------------------------------------------------------
__device__ __forceinline__ long dec8(uint32_t w) {
  uint32_t lo = w & 0x07070707u;          // mag idx n0,n2,n4,n6
  uint32_t hi = (w >> 4) & 0x07070707u;   // mag idx n1,n3,n5,n7
  uint32_t me = __builtin_amdgcn_perm(0x4C484440u, 0x3C383000u, lo);
  uint32_t mo = __builtin_amdgcn_perm(0x4C484440u, 0x3C383000u, hi);
  uint32_t e  = me | ((w & 0x08080808u) << 4);   // even nibbles + sign
  uint32_t o  = mo | (w & 0x80808080u);          // odd nibbles + sign
  uint32_t d0 = __builtin_amdgcn_perm(o, e, 0x05010400u);  // n0,n1,n2,n3
  uint32_t d1 = __builtin_amdgcn_perm(o, e, 0x07030602u);  // n4,n5,n6,n7
  return (long)(((uint64_t)d1 << 32) | d0);
}

// ---------------------------------------------------------------------------
// 8 consecutive f32 -> fp8 hi plane (8 bytes) + fp8 residual plane (8 bytes).
// ---------------------------------------------------------------------------
__device__ __forceinline__ void quant8(const float* p, long& hi, long& lo) {
  f32x4 a = *(const f32x4*)p;
  f32x4 b = *(const f32x4*)(p + 4);
  uint32_t h0 = 0, h1 = 0;
  h0 = __builtin_amdgcn_cvt_pk_fp8_f32(a[0], a[1], h0, false);
  h0 = __builtin_amdgcn_cvt_pk_fp8_f32(a[2], a[3], h0, true);
  h1 = __builtin_amdgcn_cvt_pk_fp8_f32(b[0], b[1], h1, false);
  h1 = __builtin_amdgcn_cvt_pk_fp8_f32(b[2], b[3], h1, true);
  float r0 = a[0] - __builtin_amdgcn_cvt_f32_fp8(h0, 0);
  float r1 = a[1] - __builtin_amdgcn_cvt_f32_fp8(h0, 1);
  float r2 = a[2] - __builtin_amdgcn_cvt_f32_fp8(h0, 2);
  float r3 = a[3] - __builtin_amdgcn_cvt_f32_fp8(h0, 3);
  float r4 = b[0] - __builtin_amdgcn_cvt_f32_fp8(h1, 0);
  float r5 = b[1] - __builtin_amdgcn_cvt_f32_fp8(h1, 1);
  float r6 = b[2] - __builtin_amdgcn_cvt_f32_fp8(h1, 2);
  float r7 = b[3] - __builtin_amdgcn_cvt_f32_fp8(h1, 3);
  uint32_t l0 = 0, l1 = 0;
  l0 = __builtin_amdgcn_cvt_pk_fp8_f32(r0, r1, l0, false);
  l0 = __builtin_amdgcn_cvt_pk_fp8_f32(r2, r3, l0, true);
  l1 = __builtin_amdgcn_cvt_pk_fp8_f32(r4, r5, l1, false);
  l1 = __builtin_amdgcn_cvt_pk_fp8_f32(r6, r7, l1, true);
  hi = (long)(((uint64_t)h1 << 32) | h0);
  lo = (long)(((uint64_t)l1 << 32) | l0);
}

// ---------------------------------------------------------------------------
// K1 (prep fused in): hp[kh][32][4096] = x @ dequant(W_gu)  (f32 partials)
// 256 wgs x 1024 thr (1 wg/CU, 4 waves/SIMD): wg = 32-col tile x K-half.
// 16 waves = one 128-wide scale group each; A-fragments quantized from f32 x
// in-register (fp8 hi + residual lo); exact f32 scale FMA; 16-way LDS reduce.
// Layouts: A[m=lane&15][k=q*8+j]; B[k=q*8+j][n=lane&15]; C col=r,row=q*4+reg.
// ---------------------------------------------------------------------------
__global__ __launch_bounds__(1024, 4) void k_gateup(
    const float* __restrict__ x, const uint32_t* __restrict__ wp,
    const float* __restrict__ sc, float* __restrict__ hp) {
  __shared__ float lds[16 * 1024];
  const int nt = blockIdx.x >> 1;          // 0..127 (32-col tile)
  const int kh = blockIdx.x & 1;           // K half
  const int wid = threadIdx.x >> 6, lane = threadIdx.x & 63;
  const int q = lane >> 4, r = lane & 15;
  const int n0 = nt * 32;
  const int nA = n0 + r, nB = n0 + 16 + r;

  const int koff = kh * 2048 + wid * 128 + q * 8;    // elem offset in K
  const float* px0 = x + r * Hv + koff;
  const float* px1 = x + (r + 16) * Hv + koff;
  const uint32_t* pbA = wp + (size_t)(kh * 256 + wid * 16 + q) * N1 + nA;
  const uint32_t* pbB = pbA + 16;

  f32x4 t00 = {0,0,0,0}, t01 = {0,0,0,0}, t10 = {0,0,0,0}, t11 = {0,0,0,0};
  #pragma unroll
  for (int st = 0; st < 4; ++st) {         // 4 x K=32 steps = one group
    long A0h, A0l, A1h, A1l;
    quant8(px0 + st * 32, A0h, A0l);
    quant8(px1 + st * 32, A1h, A1l);
    long BA = dec8(pbA[(size_t)st * 4 * N1]);
    long BB = dec8(pbB[(size_t)st * 4 * N1]);
    t00 = __builtin_amdgcn_mfma_f32_16x16x32_fp8_fp8(A0h, BA, t00, 0, 0, 0);
    t00 = __builtin_amdgcn_mfma_f32_16x16x32_fp8_fp8(A0l, BA, t00, 0, 0, 0);
    t01 = __builtin_amdgcn_mfma_f32_16x16x32_fp8_fp8(A0h, BB, t01, 0, 0, 0);
    t01 = __builtin_amdgcn_mfma_f32_16x16x32_fp8_fp8(A0l, BB, t01, 0, 0, 0);
    t10 = __builtin_amdgcn_mfma_f32_16x16x32_fp8_fp8(A1h, BA, t10, 0, 0, 0);
    t10 = __builtin_amdgcn_mfma_f32_16x16x32_fp8_fp8(A1l, BA, t10, 0, 0, 0);
    t11 = __builtin_amdgcn_mfma_f32_16x16x32_fp8_fp8(A1h, BB, t11, 0, 0, 0);
    t11 = __builtin_amdgcn_mfma_f32_16x16x32_fp8_fp8(A1l, BB, t11, 0, 0, 0);
  }
  const int g = kh * 16 + wid;             // this wave's scale group
  const float sA = sc[g * N1 + nA];
  const float sB = sc[g * N1 + nB];
  float* my = lds + wid * 1024;
  #pragma unroll
  for (int j = 0; j < 4; ++j) {
    const int rw = q * 4 + j;
    my[rw * 32 + r]             = sA * t00[j];
    my[rw * 32 + 16 + r]        = sB * t01[j];
    my[(16 + rw) * 32 + r]      = sA * t10[j];
    my[(16 + rw) * 32 + 16 + r] = sB * t11[j];
  }
  __syncthreads();
  const int i = threadIdx.x;               // 1024 outputs (32x32)
  float sum = 0.f;
  #pragma unroll
  for (int w = 0; w < 16; ++w) sum += lds[w * 1024 + i];
  hp[(size_t)kh * (Bv * N1) + (i >> 5) * N1 + n0 + (i & 31)] = sum;
}

// ---------------------------------------------------------------------------
// K2: SwiGLU over 2 f32 partial planes -> two fp8 planes of act [32,2048].
// 256 wgs x 64 thr (all CUs touched; pure geometry remap of the R9 kernel).
// Clamp to +-440 (OCP e4m3 overflow->NaN armor; true |act| <~ 25).
// ---------------------------------------------------------------------------
__global__ __launch_bounds__(64) void k_swiglu(const float* __restrict__ hp,
                                               uint32_t* __restrict__ ah,
                                               uint32_t* __restrict__ al) {
  const int t = blockIdx.x * 64 + threadIdx.x;  // 16384 threads, 4 elems each
  const int m = t >> 9;
  const int c = (t & 511) * 4;
  constexpr int P = Bv * N1;
  const float* pg = hp + m * N1 + c;
  const float* pu = pg + Iv;
  f32x4 g = *(const f32x4*)pg + *(const f32x4*)(pg + P);
  f32x4 u = *(const f32x4*)pu + *(const f32x4*)(pu + P);
  float a[4];
  #pragma unroll
  for (int j = 0; j < 4; ++j) {
    float gv = g[j];
    float av = gv / (1.0f + __expf(-gv)) * u[j];
    a[j] = fminf(fmaxf(av, -440.0f), 440.0f);
  }
  uint32_t h = 0;
  h = __builtin_amdgcn_cvt_pk_fp8_f32(a[0], a[1], h, false);
  h = __builtin_amdgcn_cvt_pk_fp8_f32(a[2], a[3], h, true);
  float r0 = a[0] - __builtin_amdgcn_cvt_f32_fp8(h, 0);
  float r1 = a[1] - __builtin_amdgcn_cvt_f32_fp8(h, 1);
  float r2 = a[2] - __builtin_amdgcn_cvt_f32_fp8(h, 2);
  float r3 = a[3] - __builtin_amdgcn_cvt_f32_fp8(h, 3);
  uint32_t l = 0;
  l = __builtin_amdgcn_cvt_pk_fp8_f32(r0, r1, l, false);
  l = __builtin_amdgcn_cvt_pk_fp8_f32(r2, r3, l, true);
  ah[t] = h; al[t] = l;
}

// ---------------------------------------------------------------------------
// K3: out f32 [32][4096] = act[32,2048] @ dequant(W_down).
// 256 wgs x 1024 thr: wg = 16-col tile x full K(2048). 16 waves = one scale
// group each; both row-tiles per wave; 16-way LDS reduce; direct f32 out.
// ---------------------------------------------------------------------------
__global__ __launch_bounds__(1024, 4) void k_down(
    const uint8_t* __restrict__ ah8, const uint8_t* __restrict__ al8,
    const uint32_t* __restrict__ wp, const float* __restrict__ sc,
    float* __restrict__ out) {
  __shared__ float lds[16 * 512];
  const int n0 = blockIdx.x * 16;
  const int wid = threadIdx.x >> 6, lane = threadIdx.x & 63;
  const int q = lane >> 4, r = lane & 15;
  const int n = n0 + r;

  const int koff = wid * 128 + q * 8;
  const uint8_t* pa0h = ah8 + r * Iv + koff;
  const uint8_t* pa0l = al8 + r * Iv + koff;
  const uint8_t* pa1h = ah8 + (r + 16) * Iv + koff;
  const uint8_t* pa1l = al8 + (r + 16) * Iv + koff;
  const uint32_t* pb = wp + (size_t)(wid * 16 + q) * Hv + n;

  f32x4 t0 = {0,0,0,0}, t1 = {0,0,0,0};
  #pragma unroll
  for (int st = 0; st < 4; ++st) {
    long A0h = *(const long*)(pa0h + st * 32);
    long A0l = *(const long*)(pa0l + st * 32);
    long A1h = *(const long*)(pa1h + st * 32);
    long A1l = *(const long*)(pa1l + st * 32);
    long Bf = dec8(pb[(size_t)st * 4 * Hv]);
    t0 = __builtin_amdgcn_mfma_f32_16x16x32_fp8_fp8(A0h, Bf, t0, 0, 0, 0);
    t0 = __builtin_amdgcn_mfma_f32_16x16x32_fp8_fp8(A0l, Bf, t0, 0, 0, 0);
    t1 = __builtin_amdgcn_mfma_f32_16x16x32_fp8_fp8(A1h, Bf, t1, 0, 0, 0);
    t1 = __builtin_amdgcn_mfma_f32_16x16x32_fp8_fp8(A1l, Bf, t1, 0, 0, 0);
  }
  const float sv = sc[wid * Hv + n];
  float* my = lds + wid * 512;
  #pragma unroll
  for (int j = 0; j < 4; ++j) {
    const int rw = q * 4 + j;
    my[rw * 16 + r]        = sv * t0[j];
    my[(16 + rw) * 16 + r] = sv * t1[j];
  }
  __syncthreads();
  const int i = threadIdx.x;
  if (i < 512) {                            // 512 outputs (32x16)
    float sum = 0.f;
    #pragma unroll
    for (int w = 0; w < 16; ++w) sum += lds[w * 512 + i];
    out[(i >> 4) * N1 + n0 + (i & 15)] = sum;
  }
}

// ---------------------------------------------------------------------------
extern "C" void kernel_launch(void* const* d_in, const int* in_sizes, int n_in,
                              void* d_out, int out_size, void* d_ws, size_t ws_size,
                              hipStream_t stream) {
  // Harness promotes float16 tensors to float32. x, scales, out are f32.
  const float*    x   = (const float*)d_in[0];      // f32 [32,4096]
  const uint32_t* gup = (const uint32_t*)d_in[1];   // [512,4096] packed fp4
  const float*    gus = (const float*)d_in[2];      // f32 [32,4096]
  const uint32_t* dnp = (const uint32_t*)d_in[3];   // [256,4096] packed fp4
  const float*    dns = (const float*)d_in[4];      // f32 [16,4096]

  float*   hp  = (float*)d_ws;                      // [2][32][4096] f32 = 1 MiB
  uint8_t* a8h = (uint8_t*)d_ws + 2*(size_t)Bv*N1*sizeof(float);
  uint8_t* a8l = a8h + Bv*Iv;                       // 64 KiB each

  k_gateup<<<256, 1024, 0, stream>>>(x, gup, gus, hp);
  k_swiglu<<<256,   64, 0, stream>>>(hp, (uint32_t*)a8h, (uint32_t*)a8l);
  k_down  <<<256, 1024, 0, stream>>>(a8h, a8l, dnp, dns, (float*)d_out);
}